// Round 20
// baseline (322.855 us; speedup 1.0000x reference)
//
#include <hip/hip_runtime.h>
#include <hip/hip_fp16.h>
#include <math.h>

// FFA: x (4,2,2^21) f32, bins in {128..131}, fold -> 16384 rows -> 14-stage FFA ->
// SNR=(max-median)/std/sqrt(16384-added). out = periods(65536) ++ snr(8*65536).
//
// R20 = R19 bodies (wave-local loaders, 3 barriers/pass, std folded into passB)
// launched SERIALLY per bin (R18 structure). R19's mega-merge regressed (+19 us on
// passB aggregate: lost per-bin LLC locality, no occupancy benefit at 1024 blocks);
// unbundle keeps the wins, drops the merge.

typedef unsigned int u32;

#define T_LEN   2097152
#define RTOT    16384
#define YSTR    70                // y & LDS row stride in DWORDS (=140 halves)
#define B_BUF_DW (128 * YSTR)     // 8960 dwords per buffer
#define PP_LDS_BYTES (2 * B_BUF_DW * 4)      // 71680 (ping-pong) -> 2 blocks/CU

#define WS_PART_OFF 0
#define WS_Y_OFF    33024
#define WS_NEEDED   (33024 + (size_t)8 * RTOT * YSTR * 4)   // ~36.7 MB

#define HINF2 0x7C007C00u   // +inf, +inf
#define NINF2 0xFC00FC00u   // -inf, -inf

__device__ __forceinline__ u32 alnp(u32 lo, u32 hi) { return (lo >> 16) | (hi << 16); }
__device__ __forceinline__ __half2 asH2(u32 v) { union { u32 u; __half2 h; } x; x.u = v; return x.h; }
__device__ __forceinline__ u32 asU32(__half2 h) { union { u32 u; __half2 h2; } x; x.h2 = h; return x.u; }
__device__ __forceinline__ u32 hmin2u(u32 a, u32 b) {
  u32 r; asm("v_pk_min_f16 %0, %1, %2" : "=v"(r) : "v"(a), "v"(b)); return r;
}
__device__ __forceinline__ u32 hmax2u(u32 a, u32 b) {
  u32 r; asm("v_pk_max_f16 %0, %1, %2" : "=v"(r) : "v"(a), "v"(b)); return r;
}

// ---------------- periods (np.linspace semantics, f64 then cast) ---------------------
__global__ void k_periods(float* __restrict__ out) {
  int i = blockIdx.x * 256 + threadIdx.x;   // 65536
  int bi = i >> 14, j = i & 16383;
  double tsamp = 6.4e-05;
  double p0 = tsamp * (double)(128 + bi);
  double p1 = tsamp * (double)(129 + bi);
  double step = (p1 - p0) / 16383.0;
  double v = (j == 16383) ? p1 : (p0 + (double)j * step);
  out[i] = (float)v;
}

// ---------------- fp16 radix-4 window: out[0..3] for col-pair at c0 ------------------
// Verified algebra (R8..R19): out[o] cols {c0,c0+1} = a + V1[1-(o>>1)] + V2[2-((o+1)>>1)]
// + V3[3-o]; Vk[m] = half2 at cols (qk+m, qk+m+1); qk = c0 - s_kp (single wrap).
__device__ __forceinline__ void pair16_col(const u32* r0p, const u32* r1p,
                                           const u32* r2p, const u32* r3p,
                                           int c0, int s1p, int s2p, int s3p,
                                           int ncol, u32 outw[4]) {
  u32 a = r0p[c0 >> 1];
  int q1 = c0 - s1p; if (q1 < 0) q1 += ncol;
  int q2 = c0 - s2p; if (q2 < 0) q2 += ncol;
  int q3 = c0 - s3p; if (q3 < 0) q3 += ncol;
  int b1 = q1 >> 1, o1 = q1 & 1;
  int b2 = q2 >> 1, o2 = q2 & 1;
  int b3 = q3 >> 1, o3 = q3 & 1;
  u32 d10 = r1p[b1], d11 = r1p[b1 + 1];
  u32 d20 = r2p[b2], d21 = r2p[b2 + 1], d22 = r2p[b2 + 2];
  u32 d30 = r3p[b3], d31 = r3p[b3 + 1], d32 = r3p[b3 + 2];
  u32 a1m = alnp(d10, d11);
  u32 a2a = alnp(d20, d21), a2b = alnp(d21, d22);
  u32 a3a = alnp(d30, d31), a3b = alnp(d31, d32);
  u32 V1[2] = { o1 ? a1m : d10,  o1 ? d11 : a1m };
  u32 V2[3] = { o2 ? a2a : d20,  o2 ? d21 : a2a,  o2 ? a2b : d21 };
  u32 V3[4] = { o3 ? a3a : d30,  o3 ? d31 : a3a,  o3 ? a3b : d31,  o3 ? d32 : a3b };
#pragma unroll
  for (int o = 0; o < 4; ++o) {
    int d1 = 1 - (o >> 1);
    int d2 = 2 - ((o + 1) >> 1);
    int d3 = 3 - o;
    __half2 rr = __hadd2(__hadd2(asH2(a), asH2(V1[d1])),
                         __hadd2(asH2(V2[d2]), asH2(V3[d3])));
    outw[o] = asU32(rr);
  }
}

// ---------------- fp16 fused radix-4 stage pair, ping-pong (src -> dst) --------------
// BAR=false allowed only when this pair's sources are wave-local (ST=1 after a
// wave-local loader): per-wave LDS program order covers the dependency.
template <int NCOL, int ST, bool BAR>
__device__ __forceinline__ void ffa_pair16(const u32* src, u32* dst, int rextra) {
  int t = threadIdx.x;
  int Q = t >> 5;                 // quad-group 0..31 -> output rows 4Q..4Q+3
  int l = t & 31;                 // col-pair lane: cols {2l,2l+1}, {64+2l,65+2l}
  constexpr int g = 1 << ST;
  int q = Q & ((g >> 1) - 1);
  int B = (Q >> (ST - 1)) << (ST + 1);
  int e1 = (rextra << (ST - 1)) % NCOL;
  int e2m = (rextra << ST) % NCOL;
  int s1 = q + e1; if (s1 >= NCOL) s1 -= NCOL;
  int s2 = 2 * q + e2m; if (s2 >= NCOL) s2 -= NCOL;
  int s3 = s1 + s2; if (s3 >= NCOL) s3 -= NCOL;
  int s1p = s1 + 1; if (s1p >= NCOL) s1p -= NCOL;
  int s2p = s2 + 2; if (s2p >= NCOL) s2p -= NCOL;
  int s3p = s3 + 3; if (s3p >= NCOL) s3p -= NCOL;
  const u32* r0p = src + (size_t)(B + q) * YSTR;
  const u32* r1p = r0p + (size_t)(g >> 1) * YSTR;
  const u32* r2p = r0p + (size_t)g * YSTR;
  const u32* r3p = r2p + (size_t)(g >> 1) * YSTR;

  if constexpr (BAR) __syncthreads();   // previous stage's writes (to src) visible

  u32 outm[2][4];
  pair16_col(r0p, r1p, r2p, r3p, 2 * l,      s1p, s2p, s3p, NCOL, outm[0]);
  pair16_col(r0p, r1p, r2p, r3p, 2 * l + 64, s1p, s2p, s3p, NCOL, outm[1]);
  u32 outt[4];
  bool tact0 = (NCOL > 128) && (l == 0);   // cols 128,129 (dword 64)
  bool tact1 = (NCOL == 131) && (l == 1);  // col 130 (dword 65 lo)
  if (tact0) pair16_col(r0p, r1p, r2p, r3p, 128, s1p, s2p, s3p, NCOL, outt);
  if (tact1) pair16_col(r0p, r1p, r2p, r3p, 130, s1p, s2p, s3p, NCOL, outt);

  // no second barrier: dst != src (ping-pong), no in-place hazard
#pragma unroll
  for (int p = 0; p < 2; ++p)
#pragma unroll
    for (int o = 0; o < 4; ++o)
      dst[(size_t)(B + 4 * q + o) * YSTR + l + 32 * p] = outm[p][o];
  if (l < 3) {                    // halo halves N+2l, N+2l+1 <- cols 2l, 2l+1
#pragma unroll
    for (int o = 0; o < 4; ++o) {
      __half* hr = (__half*)(dst + (size_t)(B + 4 * q + o) * YSTR);
      __half2 hv = asH2(outm[0][o]);
      hr[NCOL + 2 * l]     = __low2half(hv);
      hr[NCOL + 2 * l + 1] = __high2half(hv);
    }
  }
  if (tact0) {
#pragma unroll
    for (int o = 0; o < 4; ++o) {
      __half* hr = (__half*)(dst + (size_t)(B + 4 * q + o) * YSTR);
      __half2 hv = asH2(outt[o]);
      hr[128] = __low2half(hv);
      if (NCOL > 129) hr[129] = __high2half(hv);
    }
  }
  if (tact1) {
#pragma unroll
    for (int o = 0; o < 4; ++o) {
      __half* hr = (__half*)(dst + (size_t)(B + 4 * q + o) * YSTR);
      hr[130] = __low2half(asH2(outt[o]));
    }
  }
}

// ---------------- pass A: x->fp16 wave-local fold + stages 1..6; stage 7 -> y --------
template <int NCOL, bool STD>
__global__ __launch_bounds__(1024, 8) void k_passA(const float* __restrict__ x,
                                                   u32* __restrict__ y,
                                                   double* __restrict__ part,
                                                   int rows_actual) {
  extern __shared__ u32 lds16[];
  __shared__ double sm2[32];
  u32* buf0 = lds16;
  u32* buf1 = lds16 + B_BUF_DW;
  int G = blockIdx.x, bc = blockIdx.y, t = threadIdx.x;
  int w = t >> 6, lane = t & 63;
  const float* src = x + (size_t)bc * T_LEN + (size_t)G * 128 * NCOL;
  double ds = 0.0, ds2 = 0.0;

  if constexpr (NCOL == 128) {
    // wave w loads its own rows 8w..8w+7 (float4 idx [w*256, w*256+256))
    const float4* src4 = (const float4*)src;
#pragma unroll
    for (int i = 0; i < 4; ++i) {
      int idx = w * 256 + lane + 64 * i;
      float4 v = src4[idx];
      if (STD) {
        ds  += (double)(v.x + v.y + v.z + v.w);
        ds2 += (double)(v.x * v.x + v.y * v.y + v.z * v.z + v.w * v.w);
      }
      int k = idx >> 5, c = (idx & 31) * 4;
      uint2 pk;
      pk.x = asU32(__floats2half2_rn(v.x, v.y));
      pk.y = asU32(__floats2half2_rn(v.z, v.w));
      *(uint2*)(buf0 + k * YSTR + (c >> 1)) = pk;
      if (c < 8) *(uint2*)(buf0 + k * YSTR + 64 + (c >> 1)) = pk;   // halo 128..135
    }
    (void)rows_actual;
  } else {
    // wave w loads float2 range [4*NCOL*w, 4*NCOL*(w+1)) = its rows 8w..8w+7
    int rowlim = rows_actual - G * 128;
    int lim = rowlim * NCOL;
    __half* hb = (__half*)buf0;
    int base2 = 4 * NCOL * w;
#pragma unroll
    for (int i = 0; i < 9; ++i) {
      int e2 = base2 + lane + 64 * i;
      if (e2 < base2 + 4 * NCOL) {
        int e = e2 * 2;
        float2 v = make_float2(0.f, 0.f);
        if (e + 1 < lim) {
          v = *(const float2*)(src + e);
        } else if (e < lim) {
          v.x = src[e];
        }
        int k = e / NCOL, c = e % NCOL;
        __half h0 = __float2half_rn(v.x), h1 = __float2half_rn(v.y);
        hb[k * 140 + c] = h0;
        if (c < 6) hb[k * 140 + NCOL + c] = h0;
        int k2 = k, c2 = c + 1;
        if (c2 == NCOL) { c2 = 0; ++k2; }     // stays within the wave's rows
        hb[k2 * 140 + c2] = h1;
        if (c2 < 6) hb[k2 * 140 + NCOL + c2] = h1;
      }
    }
  }
  if (STD) {
    for (int off = 32; off > 0; off >>= 1) {
      ds  += __shfl_down(ds, off);
      ds2 += __shfl_down(ds2, off);
    }
    if (lane == 0) { sm2[w] = ds; sm2[16 + w] = ds2; }
    // visibility for t==0's final read via the ST=3/ST=5/final barriers
  }

  ffa_pair16<NCOL, 1, false>(buf0, buf1, 0);   // wave-local: no barrier needed
  ffa_pair16<NCOL, 3, true >(buf1, buf0, 0);
  ffa_pair16<NCOL, 5, true >(buf0, buf1, 0);
  __syncthreads();                             // buf1 final (stage-6 state)

  // stage 7 fp16 -> y (row v -> ws row v*128+G), halo cols [N, N+6) mirrored
  {
    int p = t >> 4, hh = t & 15;
    const u32* ra = buf1 + (size_t)p * YSTR;
    const u32* rb = buf1 + (size_t)(p + 64) * YSTR;
    u32* dstE = y + ((size_t)bc * RTOT + (size_t)(2 * p) * 128 + G) * YSTR;
    u32* dstO = dstE + (size_t)128 * YSTR;
#pragma unroll
    for (int i = 0; i < 4; ++i) {
      int i0 = hh + 16 * i;
      int j0 = 2 * i0;
      u32 a = ra[i0];
      int qe = j0 - p;  if (qe < 0) qe += NCOL;   // even-row b base col
      int qo = qe - 1;  if (qo < 0) qo += NCOL;   // odd-row b base col
      u32 be, bo;
      { int bb = qe >> 1; u32 e0 = rb[bb], e1v = rb[bb + 1];
        be = (qe & 1) ? alnp(e0, e1v) : e0; }
      { int bb = qo >> 1; u32 e0 = rb[bb], e1v = rb[bb + 1];
        bo = (qo & 1) ? alnp(e0, e1v) : e0; }
      u32 ve = asU32(__hadd2(asH2(a), asH2(be)));
      u32 vo = asU32(__hadd2(asH2(a), asH2(bo)));
      dstE[i0] = ve;
      dstO[i0] = vo;
      if (i == 0 && hh < 3) {       // halo halves N+j0, N+j0+1 <- cols j0, j0+1
        __half* hE = (__half*)dstE;
        __half* hO = (__half*)dstO;
        __half2 hve = asH2(ve), hvo = asH2(vo);
        hE[NCOL + j0]     = __low2half(hve);
        hE[NCOL + j0 + 1] = __high2half(hve);
        hO[NCOL + j0]     = __low2half(hvo);
        hO[NCOL + j0 + 1] = __high2half(hvo);
      }
    }
    if (NCOL > 128 && hh == 0) {     // cols 128 (,129): dword 64
      int j0 = 128;
      u32 a = ra[64];
      int qe = j0 - p;                 // >= 65: no wrap
      int qo = qe - 1;
      u32 be, bo;
      { int bb = qe >> 1; u32 e0 = rb[bb], e1v = rb[bb + 1];
        be = (qe & 1) ? alnp(e0, e1v) : e0; }
      { int bb = qo >> 1; u32 e0 = rb[bb], e1v = rb[bb + 1];
        bo = (qo & 1) ? alnp(e0, e1v) : e0; }
      u32 ve = asU32(__hadd2(asH2(a), asH2(be)));
      u32 vo = asU32(__hadd2(asH2(a), asH2(bo)));
      if (NCOL > 129) {
        dstE[64] = ve; dstO[64] = vo;
      } else {
        ((__half*)dstE)[128] = __low2half(asH2(ve));
        ((__half*)dstO)[128] = __low2half(asH2(vo));
      }
    }
    if (NCOL == 131 && hh == 1) {    // col 130 (dword 65 lo)
      int j0 = 130;
      u32 a = ra[65];
      int qe = j0 - p;
      int qo = qe - 1;
      u32 be, bo;
      { int bb = qe >> 1; u32 e0 = rb[bb], e1v = rb[bb + 1];
        be = (qe & 1) ? alnp(e0, e1v) : e0; }
      { int bb = qo >> 1; u32 e0 = rb[bb], e1v = rb[bb + 1];
        bo = (qo & 1) ? alnp(e0, e1v) : e0; }
      ((__half*)dstE)[130] = __low2half(__hadd2(asH2(a), asH2(be)));
      ((__half*)dstO)[130] = __low2half(__hadd2(asH2(a), asH2(bo)));
    }
  }

  if (STD && t == 0) {
    double s = 0.0, s2 = 0.0;
#pragma unroll
    for (int ww = 0; ww < 16; ++ww) { s += sm2[ww]; s2 += sm2[16 + ww]; }
    part[(bc * 128 + G) * 2]     = s;
    part[(bc * 128 + G) * 2 + 1] = s2;
  }
}

// ---------------- pass B: wave-local load, stages 8..13, stage14+SNR (std inline) ----
template <int NCOL>
__global__ __launch_bounds__(1024, 8) void k_passB(const u32* __restrict__ y,
                                                   const double* __restrict__ part,
                                                   float* __restrict__ out,
                                                   int added, int bins_idx) {
  extern __shared__ u32 lds16[];
  __shared__ float s_denom;
  u32* buf0 = lds16;
  u32* buf1 = lds16 + B_BUF_DW;
  int r = blockIdx.x, bc = blockIdx.y, t = threadIdx.x;
  int w = t >> 6, lane = t & 63;

  // std denom from per-block partials (wave 0; visible to all after later barriers)
  if (t < 64) {
    double s  = part[(bc * 128 + t) * 2]     + part[(bc * 128 + t + 64) * 2];
    double s2 = part[(bc * 128 + t) * 2 + 1] + part[(bc * 128 + t + 64) * 2 + 1];
    for (int off = 32; off > 0; off >>= 1) {
      s  += __shfl_down(s, off);
      s2 += __shfl_down(s2, off);
    }
    if (t == 0) {
      double N = (double)T_LEN;
      double var = (s2 - s * s / N) / (N - 1.0);
      s_denom = (float)(sqrt(var) * sqrt((double)(RTOT - added)));
    }
  }

  // wave-local loader: wave w copies its rows 8w..8w+7 (uint4 [w*140, w*140+140))
  const uint4* src4 = (const uint4*)(y + ((size_t)bc * RTOT + (size_t)r * 128) * YSTR);
#pragma unroll
  for (int i = 0; i < 3; ++i) {
    int idx = lane + 64 * i;
    if (idx < 140) *(uint4*)(buf0 + (w * 140 + idx) * 4) = src4[w * 140 + idx];
  }

  ffa_pair16<NCOL, 1, false>(buf0, buf1, r);   // wave-local: no barrier needed
  ffa_pair16<NCOL, 3, true >(buf1, buf0, r);
  ffa_pair16<NCOL, 5, true >(buf0, buf1, r);
  __syncthreads();                             // buf1 final; buf0 dead -> hist space

  // ---- stage 14 fused with SNR, packed fp16 ----
  int u = t >> 3, h = t & 7;      // 8 threads/row
  int p = u >> 1;
  int extra = (r << 6) % NCOL;
  int s = p + extra; if (s >= NCOL) s -= NCOL;
  s += (u & 1);      if (s >= NCOL) s -= NCOL;
  const u32* ra = buf1 + (size_t)p * YSTR;
  const u32* rb = buf1 + (size_t)(p + 64) * YSTR;
  constexpr int NCHUNK = (NCOL + 3) / 4;
  constexpr int NCK = (NCHUNK + 7) / 8;       // 4 (NCOL=128) or 5
  u32 valp[NCK * 2];
  u32 mn2 = HINF2, mx2 = NINF2;
#pragma unroll
  for (int i = 0; i < NCK; ++i) {
    if (NCOL <= 128 || i < 4) {               // full chunk (all 4 cols valid)
      int ch = h + 8 * i;
      int j0 = ch * 4;
      uint2 aa = *(const uint2*)(ra + 2 * ch);
      int q0 = j0 - s; if (q0 < 0) q0 += NCOL;
      int bb = q0 >> 1, ob = q0 & 1;
      u32 e0 = rb[bb], e1 = rb[bb + 1], e2 = rb[bb + 2];
      u32 blo = ob ? alnp(e0, e1) : e0;
      u32 bhi = ob ? alnp(e1, e2) : e1;
      u32 v0 = asU32(__hadd2(asH2(aa.x), asH2(blo)));
      u32 v1 = asU32(__hadd2(asH2(aa.y), asH2(bhi)));
      valp[2 * i]     = v0;
      valp[2 * i + 1] = v1;
      mn2 = hmin2u(hmin2u(mn2, v0), v1);
      mx2 = hmax2u(hmax2u(mx2, v0), v1);
    } else {                                  // i==4, NCOL>128: tail chunk (h==0)
      if (h == 0) {
        constexpr int j0 = 128;
        uint2 aa = *(const uint2*)(ra + 64);
        int q0 = j0 - s; if (q0 < 0) q0 += NCOL;
        int bb = q0 >> 1, ob = q0 & 1;
        u32 e0 = rb[bb], e1 = rb[bb + 1], e2 = rb[bb + 2];
        u32 blo = ob ? alnp(e0, e1) : e0;
        u32 bhi = ob ? alnp(e1, e2) : e1;
        u32 v0 = asU32(__hadd2(asH2(aa.x), asH2(blo)));
        u32 v1 = asU32(__hadd2(asH2(aa.y), asH2(bhi)));
        u32 v0mn, v1mn, v0mx, v1mx;
        if (NCOL == 129) {
          v0mn = (v0 & 0xFFFFu) | 0x7C000000u; v0mx = (v0 & 0xFFFFu) | 0xFC000000u;
          v1mn = HINF2;                        v1mx = NINF2;
        } else if (NCOL == 130) {
          v0mn = v0;                           v0mx = v0;
          v1mn = HINF2;                        v1mx = NINF2;
        } else {
          v0mn = v0;                           v0mx = v0;
          v1mn = (v1 & 0xFFFFu) | 0x7C000000u; v1mx = (v1 & 0xFFFFu) | 0xFC000000u;
        }
        valp[2 * i]     = v0mn;
        valp[2 * i + 1] = v1mn;
        mn2 = hmin2u(hmin2u(mn2, v0mn), v1mn);
        mx2 = hmax2u(hmax2u(mx2, v0mx), v1mx);
      } else {
        valp[2 * i]     = HINF2;
        valp[2 * i + 1] = HINF2;
      }
    }
  }
#pragma unroll
  for (int off = 1; off < 8; off <<= 1) {
    mn2 = hmin2u(mn2, (u32)__shfl_xor((int)mn2, off));
    mx2 = hmax2u(mx2, (u32)__shfl_xor((int)mx2, off));
  }
  float mn = fminf(__low2float(asH2(mn2)), __high2float(asH2(mn2)));
  float mx = fmaxf(__low2float(asH2(mx2)), __high2float(asH2(mx2)));

  // histogram in buf0 (dead); row u at stride 68 dwords (banks 4u%32, wave-local)
  u32* hrow = buf0 + (size_t)u * 68;
  {
    uint4 z = make_uint4(0u, 0u, 0u, 0u);
    *(uint4*)(hrow + h * 8)     = z;
    *(uint4*)(hrow + h * 8 + 4) = z;
  }
  float rng = mx - mn;
  float scale = 128.0f / fmaxf(rng, 1e-30f);
#pragma unroll
  for (int i = 0; i < NCK * 2; ++i) {
    __half2 hv = asH2(valp[i]);
    float f0 = __low2float(hv), f1 = __high2float(hv);
    int b0 = min((int)((f0 - mn) * scale), 127);   // inf saturates -> 127
    int b1 = min((int)((f1 - mn) * scale), 127);
    atomicAdd(&hrow[b0 >> 1], 1u << ((b0 & 1) * 16));
    atomicAdd(&hrow[b1 >> 1], 1u << ((b1 & 1) * 16));
  }
  int cnt[16];
  {
    uint4 c0v = *(const uint4*)(hrow + h * 8);
    uint4 c1v = *(const uint4*)(hrow + h * 8 + 4);
    u32 wv[8] = {c0v.x, c0v.y, c0v.z, c0v.w, c1v.x, c1v.y, c1v.z, c1v.w};
#pragma unroll
    for (int m = 0; m < 8; ++m) {
      cnt[2 * m]     = (int)(wv[m] & 0xFFFFu);
      cnt[2 * m + 1] = (int)(wv[m] >> 16);
    }
  }
  int local = 0;
#pragma unroll
  for (int i = 0; i < 16; ++i) local += cnt[i];
  int incl = local, tmp;
  tmp = __shfl_up(incl, 1, 8); if (h >= 1) incl += tmp;
  tmp = __shfl_up(incl, 2, 8); if (h >= 2) incl += tmp;
  tmp = __shfl_up(incl, 4, 8); if (h >= 4) incl += tmp;
  int excl = incl - local;
  constexpr int TR = ((NCOL - 1) >> 1) + 1;    // lower-median rank (1-based)
  int cum = excl, cross = 0;
#pragma unroll
  for (int i = 0; i < 16; ++i) {
    cum += cnt[i];
    cross += (cum < TR) ? 1 : 0;
  }
  int bcand = (excl < TR && TR <= incl) ? (h * 16 + cross) : (1 << 30);
#pragma unroll
  for (int off = 1; off < 8; off <<= 1)
    bcand = min(bcand, __shfl_xor(bcand, off));

  float med = mn + ((float)bcand + 0.5f) * rng * (1.0f / 128.0f);
  float snr = (mx - med) / s_denom;
  if (h == 0)
    out[65536 + (size_t)bc * 65536 + (size_t)bins_idx * RTOT + r * 128 + u] = snr;
}

// ---------------- launch -------------------------------------------------------------
extern "C" void kernel_launch(void* const* d_in, const int* in_sizes, int n_in,
                              void* d_out, int out_size, void* d_ws, size_t ws_size,
                              hipStream_t stream) {
  const float* x = (const float*)d_in[0];
  float* out = (float*)d_out;
  char* ws = (char*)d_ws;
  if (ws_size < WS_NEEDED) return;

  double* part = (double*)(ws + WS_PART_OFF);
  u32*    y    = (u32*)   (ws + WS_Y_OFF);

  (void)hipFuncSetAttribute((const void*)k_passA<128, true>,  hipFuncAttributeMaxDynamicSharedMemorySize, PP_LDS_BYTES);
  (void)hipFuncSetAttribute((const void*)k_passA<129, false>, hipFuncAttributeMaxDynamicSharedMemorySize, PP_LDS_BYTES);
  (void)hipFuncSetAttribute((const void*)k_passA<130, false>, hipFuncAttributeMaxDynamicSharedMemorySize, PP_LDS_BYTES);
  (void)hipFuncSetAttribute((const void*)k_passA<131, false>, hipFuncAttributeMaxDynamicSharedMemorySize, PP_LDS_BYTES);
  (void)hipFuncSetAttribute((const void*)k_passB<128>, hipFuncAttributeMaxDynamicSharedMemorySize, PP_LDS_BYTES);
  (void)hipFuncSetAttribute((const void*)k_passB<129>, hipFuncAttributeMaxDynamicSharedMemorySize, PP_LDS_BYTES);
  (void)hipFuncSetAttribute((const void*)k_passB<130>, hipFuncAttributeMaxDynamicSharedMemorySize, PP_LDS_BYTES);
  (void)hipFuncSetAttribute((const void*)k_passB<131>, hipFuncAttributeMaxDynamicSharedMemorySize, PP_LDS_BYTES);

  k_periods<<<256, 256, 0, stream>>>(out);

  // bins=128: rows=16384; 129: 16256; 130: 16131; 131: 16008 (serial per bin;
  // stream order protects y reuse; std partials written by A<128>, read by every B)
  k_passA<128, true><<<dim3(128, 8), 1024, PP_LDS_BYTES, stream>>>(x, y, part, 16384);
  k_passB<128><<<dim3(128, 8), 1024, PP_LDS_BYTES, stream>>>(y, part, out, 0, 0);
  k_passA<129, false><<<dim3(128, 8), 1024, PP_LDS_BYTES, stream>>>(x, y, part, 16256);
  k_passB<129><<<dim3(128, 8), 1024, PP_LDS_BYTES, stream>>>(y, part, out, 128, 1);
  k_passA<130, false><<<dim3(128, 8), 1024, PP_LDS_BYTES, stream>>>(x, y, part, 16131);
  k_passB<130><<<dim3(128, 8), 1024, PP_LDS_BYTES, stream>>>(y, part, out, 253, 2);
  k_passA<131, false><<<dim3(128, 8), 1024, PP_LDS_BYTES, stream>>>(x, y, part, 16008);
  k_passB<131><<<dim3(128, 8), 1024, PP_LDS_BYTES, stream>>>(y, part, out, 376, 3);
}

// Round 21
// 266.719 us; speedup vs baseline: 1.2105x; 1.2105x over previous
//
#include <hip/hip_runtime.h>
#include <hip/hip_fp16.h>
#include <math.h>

// FFA: x (4,2,2^21) f32, bins in {128..131}, fold -> 16384 rows -> 14-stage FFA ->
// SNR=(max-median)/std/sqrt(16384-added). out = periods(65536) ++ snr(8*65536).
//
// R21 = exact revert to R18 (best: 265.2 us). R19 (mega-merge, +18) and R20
// (wave-local loaders + dropped ST=1 barrier + std-fold, +58) both regressed;
// R18's structure is the empirical optimum: fp16 ping-pong tiles both passes,
// 4 barriers/pass, packed-fp16 SNR, hist in dead buffer at stride 68.

typedef unsigned int u32;

#define T_LEN   2097152
#define RTOT    16384
#define YSTR    70                // y & LDS row stride in DWORDS (=140 halves)
#define B_BUF_DW (128 * YSTR)     // 8960 dwords per buffer
#define PP_LDS_BYTES (2 * B_BUF_DW * 4)      // 71680 (ping-pong) -> 2 blocks/CU

#define WS_PART_OFF 0
#define WS_STD_OFF  32768
#define WS_Y_OFF    33024
#define WS_NEEDED   (33024 + (size_t)8 * RTOT * YSTR * 4)   // ~36.7 MB

#define HINF2 0x7C007C00u   // +inf, +inf
#define NINF2 0xFC00FC00u   // -inf, -inf

__device__ __forceinline__ u32 alnp(u32 lo, u32 hi) { return (lo >> 16) | (hi << 16); }
__device__ __forceinline__ __half2 asH2(u32 v) { union { u32 u; __half2 h; } x; x.u = v; return x.h; }
__device__ __forceinline__ u32 asU32(__half2 h) { union { u32 u; __half2 h2; } x; x.h2 = h; return x.u; }
__device__ __forceinline__ u32 hmin2u(u32 a, u32 b) {
  u32 r; asm("v_pk_min_f16 %0, %1, %2" : "=v"(r) : "v"(a), "v"(b)); return r;
}
__device__ __forceinline__ u32 hmax2u(u32 a, u32 b) {
  u32 r; asm("v_pk_max_f16 %0, %1, %2" : "=v"(r) : "v"(a), "v"(b)); return r;
}

// ---------------- periods (np.linspace semantics, f64 then cast) ---------------------
__global__ void k_periods(float* __restrict__ out) {
  int i = blockIdx.x * 256 + threadIdx.x;   // 65536
  int bi = i >> 14, j = i & 16383;
  double tsamp = 6.4e-05;
  double p0 = tsamp * (double)(128 + bi);
  double p1 = tsamp * (double)(129 + bi);
  double step = (p1 - p0) / 16383.0;
  double v = (j == 16383) ? p1 : (p0 + (double)j * step);
  out[i] = (float)v;
}

// ---------------- std final: sum 128 per-block partials per bc (ddof=1) --------------
__global__ void k_std_final(const double* __restrict__ part, float* __restrict__ stddev) {
  int t = threadIdx.x;
  if (t < 8) {
    double s = 0.0, s2 = 0.0;
    for (int G = 0; G < 128; ++G) {
      s  += part[(t * 128 + G) * 2];
      s2 += part[(t * 128 + G) * 2 + 1];
    }
    double N = (double)T_LEN;
    double var = (s2 - s * s / N) / (N - 1.0);
    stddev[t] = (float)sqrt(var);
  }
}

// ---------------- fp16 radix-4 window: out[0..3] for col-pair at c0 ------------------
// Verified algebra (R8..R18): out[o] cols {c0,c0+1} = a + V1[1-(o>>1)] + V2[2-((o+1)>>1)]
// + V3[3-o]; Vk[m] = half2 at cols (qk+m, qk+m+1); qk = c0 - s_kp (single wrap).
__device__ __forceinline__ void pair16_col(const u32* r0p, const u32* r1p,
                                           const u32* r2p, const u32* r3p,
                                           int c0, int s1p, int s2p, int s3p,
                                           int ncol, u32 outw[4]) {
  u32 a = r0p[c0 >> 1];
  int q1 = c0 - s1p; if (q1 < 0) q1 += ncol;
  int q2 = c0 - s2p; if (q2 < 0) q2 += ncol;
  int q3 = c0 - s3p; if (q3 < 0) q3 += ncol;
  int b1 = q1 >> 1, o1 = q1 & 1;
  int b2 = q2 >> 1, o2 = q2 & 1;
  int b3 = q3 >> 1, o3 = q3 & 1;
  u32 d10 = r1p[b1], d11 = r1p[b1 + 1];
  u32 d20 = r2p[b2], d21 = r2p[b2 + 1], d22 = r2p[b2 + 2];
  u32 d30 = r3p[b3], d31 = r3p[b3 + 1], d32 = r3p[b3 + 2];
  u32 a1m = alnp(d10, d11);
  u32 a2a = alnp(d20, d21), a2b = alnp(d21, d22);
  u32 a3a = alnp(d30, d31), a3b = alnp(d31, d32);
  u32 V1[2] = { o1 ? a1m : d10,  o1 ? d11 : a1m };
  u32 V2[3] = { o2 ? a2a : d20,  o2 ? d21 : a2a,  o2 ? a2b : d21 };
  u32 V3[4] = { o3 ? a3a : d30,  o3 ? d31 : a3a,  o3 ? a3b : d31,  o3 ? d32 : a3b };
#pragma unroll
  for (int o = 0; o < 4; ++o) {
    int d1 = 1 - (o >> 1);
    int d2 = 2 - ((o + 1) >> 1);
    int d3 = 3 - o;
    __half2 rr = __hadd2(__hadd2(asH2(a), asH2(V1[d1])),
                         __hadd2(asH2(V2[d2]), asH2(V3[d3])));
    outw[o] = asU32(rr);
  }
}

// ---------------- fp16 fused radix-4 stage pair, ping-pong (src -> dst) --------------
template <int NCOL, int ST>
__device__ __forceinline__ void ffa_pair16(const u32* src, u32* dst, int rextra) {
  int t = threadIdx.x;
  int Q = t >> 5;                 // quad-group 0..31 -> output rows 4Q..4Q+3
  int l = t & 31;                 // col-pair lane: cols {2l,2l+1}, {64+2l,65+2l}
  constexpr int g = 1 << ST;
  int q = Q & ((g >> 1) - 1);
  int B = (Q >> (ST - 1)) << (ST + 1);
  int e1 = (rextra << (ST - 1)) % NCOL;
  int e2m = (rextra << ST) % NCOL;
  int s1 = q + e1; if (s1 >= NCOL) s1 -= NCOL;
  int s2 = 2 * q + e2m; if (s2 >= NCOL) s2 -= NCOL;
  int s3 = s1 + s2; if (s3 >= NCOL) s3 -= NCOL;
  int s1p = s1 + 1; if (s1p >= NCOL) s1p -= NCOL;
  int s2p = s2 + 2; if (s2p >= NCOL) s2p -= NCOL;
  int s3p = s3 + 3; if (s3p >= NCOL) s3p -= NCOL;
  const u32* r0p = src + (size_t)(B + q) * YSTR;
  const u32* r1p = r0p + (size_t)(g >> 1) * YSTR;
  const u32* r2p = r0p + (size_t)g * YSTR;
  const u32* r3p = r2p + (size_t)(g >> 1) * YSTR;

  __syncthreads();                // previous stage's writes (to src) visible

  u32 outm[2][4];
  pair16_col(r0p, r1p, r2p, r3p, 2 * l,      s1p, s2p, s3p, NCOL, outm[0]);
  pair16_col(r0p, r1p, r2p, r3p, 2 * l + 64, s1p, s2p, s3p, NCOL, outm[1]);
  u32 outt[4];
  bool tact0 = (NCOL > 128) && (l == 0);   // cols 128,129 (dword 64)
  bool tact1 = (NCOL == 131) && (l == 1);  // col 130 (dword 65 lo)
  if (tact0) pair16_col(r0p, r1p, r2p, r3p, 128, s1p, s2p, s3p, NCOL, outt);
  if (tact1) pair16_col(r0p, r1p, r2p, r3p, 130, s1p, s2p, s3p, NCOL, outt);

  // no second barrier: dst != src (ping-pong), no in-place hazard
#pragma unroll
  for (int p = 0; p < 2; ++p)
#pragma unroll
    for (int o = 0; o < 4; ++o)
      dst[(size_t)(B + 4 * q + o) * YSTR + l + 32 * p] = outm[p][o];
  if (l < 3) {                    // halo halves N+2l, N+2l+1 <- cols 2l, 2l+1
#pragma unroll
    for (int o = 0; o < 4; ++o) {
      __half* hr = (__half*)(dst + (size_t)(B + 4 * q + o) * YSTR);
      __half2 hv = asH2(outm[0][o]);
      hr[NCOL + 2 * l]     = __low2half(hv);
      hr[NCOL + 2 * l + 1] = __high2half(hv);
    }
  }
  if (tact0) {
#pragma unroll
    for (int o = 0; o < 4; ++o) {
      __half* hr = (__half*)(dst + (size_t)(B + 4 * q + o) * YSTR);
      __half2 hv = asH2(outt[o]);
      hr[128] = __low2half(hv);
      if (NCOL > 129) hr[129] = __high2half(hv);
    }
  }
  if (tact1) {
#pragma unroll
    for (int o = 0; o < 4; ++o) {
      __half* hr = (__half*)(dst + (size_t)(B + 4 * q + o) * YSTR);
      hr[130] = __low2half(asH2(outt[o]));
    }
  }
}

// ---------------- pass A: x->fp16 fold + stages 1..6 ping-pong; stage 7 -> y ---------
template <int NCOL, bool STD>
__global__ __launch_bounds__(1024, 8) void k_passA(const float* __restrict__ x,
                                                   u32* __restrict__ y,
                                                   double* __restrict__ part,
                                                   int rows_actual) {
  extern __shared__ u32 lds16[];
  __shared__ double sm2[32];
  u32* buf0 = lds16;
  u32* buf1 = lds16 + B_BUF_DW;
  int G = blockIdx.x, bc = blockIdx.y, t = threadIdx.x;

  const float* src = x + (size_t)bc * T_LEN + (size_t)G * 128 * NCOL;
  double ds = 0.0, ds2 = 0.0;

  if constexpr (NCOL == 128) {
    // no padding; float4 -> 2 packed half2 dwords, uint2-aligned; halo c<8
    const float4* src4 = (const float4*)src;
#pragma unroll
    for (int i = 0; i < 4; ++i) {
      int idx = t + i * 1024;                // < 4096
      float4 v = src4[idx];
      if (STD) {
        ds  += (double)(v.x + v.y + v.z + v.w);
        ds2 += (double)(v.x * v.x + v.y * v.y + v.z * v.z + v.w * v.w);
      }
      int k = idx >> 5, c = (idx & 31) * 4;
      uint2 pk;
      pk.x = asU32(__floats2half2_rn(v.x, v.y));
      pk.y = asU32(__floats2half2_rn(v.z, v.w));
      *(uint2*)(buf0 + k * YSTR + (c >> 1)) = pk;
      if (c < 8) *(uint2*)(buf0 + k * YSTR + 64 + (c >> 1)) = pk;   // halo 128..135
    }
    (void)rows_actual;
  } else {
    int rowlim = rows_actual - G * 128;
    int lim = rowlim * NCOL;
    __half* hb = (__half*)buf0;
    constexpr int NF2 = 128 * NCOL / 2;
#pragma unroll
    for (int i = 0; i < (NF2 + 1023) / 1024; ++i) {
      int e2 = t + i * 1024;
      if (e2 < NF2) {
        int e = e2 * 2;
        float2 v = make_float2(0.f, 0.f);
        if (e + 1 < lim) {
          v = *(const float2*)(src + e);
        } else if (e < lim) {
          v.x = src[e];
        }
        int k = e / NCOL, c = e % NCOL;
        __half h0 = __float2half_rn(v.x), h1 = __float2half_rn(v.y);
        hb[k * 140 + c] = h0;
        if (c < 6) hb[k * 140 + NCOL + c] = h0;
        int k2 = k, c2 = c + 1;
        if (c2 == NCOL) { c2 = 0; ++k2; }     // k2 <= 127 since e+1 < 128*NCOL
        hb[k2 * 140 + c2] = h1;
        if (c2 < 6) hb[k2 * 140 + NCOL + c2] = h1;
      }
    }
  }
  if (STD) {
    for (int off = 32; off > 0; off >>= 1) {
      ds  += __shfl_down(ds, off);
      ds2 += __shfl_down(ds2, off);
    }
    int wid = t >> 6, lane = t & 63;
    if (lane == 0) { sm2[wid] = ds; sm2[16 + wid] = ds2; }
    // visibility via ffa_pair16's entry barrier (t==0 reads at the very end)
  }

  ffa_pair16<NCOL, 1>(buf0, buf1, 0);    // stages 1,2 (barrier at entry)
  ffa_pair16<NCOL, 3>(buf1, buf0, 0);    // stages 3,4
  ffa_pair16<NCOL, 5>(buf0, buf1, 0);    // stages 5,6
  __syncthreads();                       // buf1 final (stage-6 state)

  // stage 7 fp16: rows 2p (shift p), 2p+1 (shift p+1) from a=buf1[p], b=buf1[p+64];
  // direct u32 stores to y (row v -> ws row v*128+G), halo cols [N, N+6) mirrored.
  {
    int p = t >> 4, hh = t & 15;
    const u32* ra = buf1 + (size_t)p * YSTR;
    const u32* rb = buf1 + (size_t)(p + 64) * YSTR;
    u32* dstE = y + ((size_t)bc * RTOT + (size_t)(2 * p) * 128 + G) * YSTR;
    u32* dstO = dstE + (size_t)128 * YSTR;
#pragma unroll
    for (int i = 0; i < 4; ++i) {
      int i0 = hh + 16 * i;
      int j0 = 2 * i0;
      u32 a = ra[i0];
      int qe = j0 - p;  if (qe < 0) qe += NCOL;   // even-row b base col
      int qo = qe - 1;  if (qo < 0) qo += NCOL;   // odd-row b base col
      u32 be, bo;
      { int bb = qe >> 1; u32 e0 = rb[bb], e1v = rb[bb + 1];
        be = (qe & 1) ? alnp(e0, e1v) : e0; }
      { int bb = qo >> 1; u32 e0 = rb[bb], e1v = rb[bb + 1];
        bo = (qo & 1) ? alnp(e0, e1v) : e0; }
      u32 ve = asU32(__hadd2(asH2(a), asH2(be)));
      u32 vo = asU32(__hadd2(asH2(a), asH2(bo)));
      dstE[i0] = ve;
      dstO[i0] = vo;
      if (i == 0 && hh < 3) {       // halo halves N+j0, N+j0+1 <- cols j0, j0+1
        __half* hE = (__half*)dstE;
        __half* hO = (__half*)dstO;
        __half2 hve = asH2(ve), hvo = asH2(vo);
        hE[NCOL + j0]     = __low2half(hve);
        hE[NCOL + j0 + 1] = __high2half(hve);
        hO[NCOL + j0]     = __low2half(hvo);
        hO[NCOL + j0 + 1] = __high2half(hvo);
      }
    }
    if (NCOL > 128 && hh == 0) {     // cols 128 (,129): dword 64
      int j0 = 128;
      u32 a = ra[64];
      int qe = j0 - p;                 // >= 65: no wrap
      int qo = qe - 1;
      u32 be, bo;
      { int bb = qe >> 1; u32 e0 = rb[bb], e1v = rb[bb + 1];
        be = (qe & 1) ? alnp(e0, e1v) : e0; }
      { int bb = qo >> 1; u32 e0 = rb[bb], e1v = rb[bb + 1];
        bo = (qo & 1) ? alnp(e0, e1v) : e0; }
      u32 ve = asU32(__hadd2(asH2(a), asH2(be)));
      u32 vo = asU32(__hadd2(asH2(a), asH2(bo)));
      if (NCOL > 129) {                // halves 128,129 both real -> dword store
        dstE[64] = ve; dstO[64] = vo;
      } else {                         // NCOL==129: half 129 belongs to halo
        ((__half*)dstE)[128] = __low2half(asH2(ve));
        ((__half*)dstO)[128] = __low2half(asH2(vo));
      }
    }
    if (NCOL == 131 && hh == 1) {    // col 130 (dword 65 lo)
      int j0 = 130;
      u32 a = ra[65];
      int qe = j0 - p;
      int qo = qe - 1;
      u32 be, bo;
      { int bb = qe >> 1; u32 e0 = rb[bb], e1v = rb[bb + 1];
        be = (qe & 1) ? alnp(e0, e1v) : e0; }
      { int bb = qo >> 1; u32 e0 = rb[bb], e1v = rb[bb + 1];
        bo = (qo & 1) ? alnp(e0, e1v) : e0; }
      ((__half*)dstE)[130] = __low2half(__hadd2(asH2(a), asH2(be)));
      ((__half*)dstO)[130] = __low2half(__hadd2(asH2(a), asH2(bo)));
    }
  }

  if (STD && t == 0) {
    double s = 0.0, s2 = 0.0;
#pragma unroll
    for (int w = 0; w < 16; ++w) { s += sm2[w]; s2 += sm2[16 + w]; }
    part[(bc * 128 + G) * 2]     = s;
    part[(bc * 128 + G) * 2 + 1] = s2;
  }
}

// ---------------- pass B: fp16 ping-pong stages 8..13; stage 14 fused into SNR -------
template <int NCOL>
__global__ __launch_bounds__(1024, 8) void k_passB(const u32* __restrict__ y,
                                                   const float* __restrict__ stddev,
                                                   float* __restrict__ out,
                                                   int added, int bins_idx) {
  extern __shared__ u32 lds16[];
  u32* buf0 = lds16;
  u32* buf1 = lds16 + B_BUF_DW;
  int r = blockIdx.x, bc = blockIdx.y, t = threadIdx.x;

  // loader: y tile layout == LDS layout -> pure linear copy into buf0 (2240 uint4)
  const uint4* src4 = (const uint4*)(y + ((size_t)bc * RTOT + (size_t)r * 128) * YSTR);
#pragma unroll
  for (int i = 0; i < 3; ++i) {
    int idx = t + i * 1024;
    if (idx < 2240) *(uint4*)(buf0 + idx * 4) = src4[idx];
  }

  ffa_pair16<NCOL, 1>(buf0, buf1, r);    // stages 8,9   (barrier at entry)
  ffa_pair16<NCOL, 3>(buf1, buf0, r);    // stages 10,11
  ffa_pair16<NCOL, 5>(buf0, buf1, r);    // stages 12,13
  __syncthreads();                       // buf1 final; buf0 now dead -> hist space

  // ---- stage 14 fused with SNR, packed fp16 throughout ----
  int u = t >> 3, h = t & 7;      // 8 threads/row
  int p = u >> 1;
  int extra = (r << 6) % NCOL;
  int s = p + extra; if (s >= NCOL) s -= NCOL;
  s += (u & 1);      if (s >= NCOL) s -= NCOL;
  const u32* ra = buf1 + (size_t)p * YSTR;
  const u32* rb = buf1 + (size_t)(p + 64) * YSTR;
  constexpr int NCHUNK = (NCOL + 3) / 4;
  constexpr int NCK = (NCHUNK + 7) / 8;       // 4 (NCOL=128) or 5
  u32 valp[NCK * 2];                          // packed half2 pairs (bucket/min view)
  u32 mn2 = HINF2, mx2 = NINF2;
#pragma unroll
  for (int i = 0; i < NCK; ++i) {
    if (NCOL <= 128 || i < 4) {               // full chunk (all 4 cols valid)
      int ch = h + 8 * i;
      int j0 = ch * 4;
      uint2 aa = *(const uint2*)(ra + 2 * ch);
      int q0 = j0 - s; if (q0 < 0) q0 += NCOL;   // b cols q0..q0+3 <= N+2 < halo end
      int bb = q0 >> 1, ob = q0 & 1;
      u32 e0 = rb[bb], e1 = rb[bb + 1], e2 = rb[bb + 2];
      u32 blo = ob ? alnp(e0, e1) : e0;
      u32 bhi = ob ? alnp(e1, e2) : e1;
      u32 v0 = asU32(__hadd2(asH2(aa.x), asH2(blo)));
      u32 v1 = asU32(__hadd2(asH2(aa.y), asH2(bhi)));
      valp[2 * i]     = v0;
      valp[2 * i + 1] = v1;
      mn2 = hmin2u(hmin2u(mn2, v0), v1);
      mx2 = hmax2u(hmax2u(mx2, v0), v1);
    } else {                                  // i==4, NCOL>128: tail chunk 32 (h==0)
      if (h == 0) {
        constexpr int j0 = 128;
        uint2 aa = *(const uint2*)(ra + 64);
        int q0 = j0 - s; if (q0 < 0) q0 += NCOL;
        int bb = q0 >> 1, ob = q0 & 1;
        u32 e0 = rb[bb], e1 = rb[bb + 1], e2 = rb[bb + 2];
        u32 blo = ob ? alnp(e0, e1) : e0;
        u32 bhi = ob ? alnp(e1, e2) : e1;
        u32 v0 = asU32(__hadd2(asH2(aa.x), asH2(blo)));
        u32 v1 = asU32(__hadd2(asH2(aa.y), asH2(bhi)));
        u32 v0mn, v1mn, v0mx, v1mx;
        if (NCOL == 129) {        // col 128 valid only
          v0mn = (v0 & 0xFFFFu) | 0x7C000000u; v0mx = (v0 & 0xFFFFu) | 0xFC000000u;
          v1mn = HINF2;                        v1mx = NINF2;
        } else if (NCOL == 130) { // cols 128,129
          v0mn = v0;                           v0mx = v0;
          v1mn = HINF2;                        v1mx = NINF2;
        } else {                  // 131: cols 128,129,130
          v0mn = v0;                           v0mx = v0;
          v1mn = (v1 & 0xFFFFu) | 0x7C000000u; v1mx = (v1 & 0xFFFFu) | 0xFC000000u;
        }
        valp[2 * i]     = v0mn;
        valp[2 * i + 1] = v1mn;
        mn2 = hmin2u(hmin2u(mn2, v0mn), v1mn);
        mx2 = hmax2u(hmax2u(mx2, v0mx), v1mx);
      } else {                                // fully invalid
        valp[2 * i]     = HINF2;
        valp[2 * i + 1] = HINF2;
      }
    }
  }
  // packed 8-lane reduce (each shfl carries 2 halves)
#pragma unroll
  for (int off = 1; off < 8; off <<= 1) {
    mn2 = hmin2u(mn2, (u32)__shfl_xor((int)mn2, off));
    mx2 = hmax2u(mx2, (u32)__shfl_xor((int)mx2, off));
  }
  float mn = fminf(__low2float(asH2(mn2)), __high2float(asH2(mn2)));
  float mx = fmaxf(__low2float(asH2(mx2)), __high2float(asH2(mx2)));

  // histogram in buf0 (dead after final barrier; all post-barrier reads hit buf1).
  // Row u hist at stride 68 dwords: banks 4u%32 distinct across the wave's 8 rows.
  u32* hrow = buf0 + (size_t)u * 68;
  {
    uint4 z = make_uint4(0u, 0u, 0u, 0u);
    *(uint4*)(hrow + h * 8)     = z;
    *(uint4*)(hrow + h * 8 + 4) = z;
  }
  float rng = mx - mn;
  float scale = 128.0f / fmaxf(rng, 1e-30f);
#pragma unroll
  for (int i = 0; i < NCK * 2; ++i) {
    __half2 hv = asH2(valp[i]);
    float f0 = __low2float(hv), f1 = __high2float(hv);
    int b0 = min((int)((f0 - mn) * scale), 127);   // inf saturates -> 127
    int b1 = min((int)((f1 - mn) * scale), 127);
    atomicAdd(&hrow[b0 >> 1], 1u << ((b0 & 1) * 16));
    atomicAdd(&hrow[b1 >> 1], 1u << ((b1 & 1) * 16));
  }
  int cnt[16];
  {
    uint4 c0v = *(const uint4*)(hrow + h * 8);
    uint4 c1v = *(const uint4*)(hrow + h * 8 + 4);
    u32 w[8] = {c0v.x, c0v.y, c0v.z, c0v.w, c1v.x, c1v.y, c1v.z, c1v.w};
#pragma unroll
    for (int m = 0; m < 8; ++m) {
      cnt[2 * m]     = (int)(w[m] & 0xFFFFu);
      cnt[2 * m + 1] = (int)(w[m] >> 16);
    }
  }
  int local = 0;
#pragma unroll
  for (int i = 0; i < 16; ++i) local += cnt[i];
  int incl = local, tmp;
  tmp = __shfl_up(incl, 1, 8); if (h >= 1) incl += tmp;
  tmp = __shfl_up(incl, 2, 8); if (h >= 2) incl += tmp;
  tmp = __shfl_up(incl, 4, 8); if (h >= 4) incl += tmp;
  int excl = incl - local;
  constexpr int TR = ((NCOL - 1) >> 1) + 1;    // lower-median rank (1-based)
  int cum = excl, cross = 0;
#pragma unroll
  for (int i = 0; i < 16; ++i) {
    cum += cnt[i];
    cross += (cum < TR) ? 1 : 0;
  }
  int bcand = (excl < TR && TR <= incl) ? (h * 16 + cross) : (1 << 30);
#pragma unroll
  for (int off = 1; off < 8; off <<= 1)
    bcand = min(bcand, __shfl_xor(bcand, off));

  float med = mn + ((float)bcand + 0.5f) * rng * (1.0f / 128.0f);
  float denom = stddev[bc] * sqrtf((float)(RTOT - added));
  float snr = (mx - med) / denom;
  if (h == 0)
    out[65536 + (size_t)bc * 65536 + (size_t)bins_idx * RTOT + r * 128 + u] = snr;
}

// ---------------- launch -------------------------------------------------------------
extern "C" void kernel_launch(void* const* d_in, const int* in_sizes, int n_in,
                              void* d_out, int out_size, void* d_ws, size_t ws_size,
                              hipStream_t stream) {
  const float* x = (const float*)d_in[0];
  float* out = (float*)d_out;
  char* ws = (char*)d_ws;
  if (ws_size < WS_NEEDED) return;

  double* part   = (double*)(ws + WS_PART_OFF);
  float*  stddev = (float*) (ws + WS_STD_OFF);
  u32*    y      = (u32*)   (ws + WS_Y_OFF);

  (void)hipFuncSetAttribute((const void*)k_passA<128, true>,  hipFuncAttributeMaxDynamicSharedMemorySize, PP_LDS_BYTES);
  (void)hipFuncSetAttribute((const void*)k_passA<129, false>, hipFuncAttributeMaxDynamicSharedMemorySize, PP_LDS_BYTES);
  (void)hipFuncSetAttribute((const void*)k_passA<130, false>, hipFuncAttributeMaxDynamicSharedMemorySize, PP_LDS_BYTES);
  (void)hipFuncSetAttribute((const void*)k_passA<131, false>, hipFuncAttributeMaxDynamicSharedMemorySize, PP_LDS_BYTES);
  (void)hipFuncSetAttribute((const void*)k_passB<128>, hipFuncAttributeMaxDynamicSharedMemorySize, PP_LDS_BYTES);
  (void)hipFuncSetAttribute((const void*)k_passB<129>, hipFuncAttributeMaxDynamicSharedMemorySize, PP_LDS_BYTES);
  (void)hipFuncSetAttribute((const void*)k_passB<130>, hipFuncAttributeMaxDynamicSharedMemorySize, PP_LDS_BYTES);
  (void)hipFuncSetAttribute((const void*)k_passB<131>, hipFuncAttributeMaxDynamicSharedMemorySize, PP_LDS_BYTES);

  k_periods<<<256, 256, 0, stream>>>(out);

  // bins=128: rows=16384; 129: 16256; 130: 16131; 131: 16008
  k_passA<128, true><<<dim3(128, 8), 1024, PP_LDS_BYTES, stream>>>(x, y, part, 16384);
  k_std_final<<<1, 64, 0, stream>>>(part, stddev);
  k_passB<128><<<dim3(128, 8), 1024, PP_LDS_BYTES, stream>>>(y, stddev, out, 0, 0);
  k_passA<129, false><<<dim3(128, 8), 1024, PP_LDS_BYTES, stream>>>(x, y, part, 16256);
  k_passB<129><<<dim3(128, 8), 1024, PP_LDS_BYTES, stream>>>(y, stddev, out, 128, 1);
  k_passA<130, false><<<dim3(128, 8), 1024, PP_LDS_BYTES, stream>>>(x, y, part, 16131);
  k_passB<130><<<dim3(128, 8), 1024, PP_LDS_BYTES, stream>>>(y, stddev, out, 253, 2);
  k_passA<131, false><<<dim3(128, 8), 1024, PP_LDS_BYTES, stream>>>(x, y, part, 16008);
  k_passB<131><<<dim3(128, 8), 1024, PP_LDS_BYTES, stream>>>(y, stddev, out, 376, 3);
}